// Round 11
// baseline (859.941 us; speedup 1.0000x reference)
//
#include <hip/hip_runtime.h>
#include <hip/hip_bf16.h>
#include <cstdint>

#define NB 64        // batch
#define ND 64        // DIM
#define NH 8         // heads
#define DH 64        // dim_head
#define NIN 512      // inner
#define NMLP 256
#define NDEPTH 4
#define NPATCH 225
#define NTOK 226
#define NSB 128      // 2*B (both streams batched)
#define NROWS (NSB*NTOK)   // 28928

#define VP 248       // vt pitch (u16): 124 dw/row -> 8 bank-groups, 16B-aligned reads

typedef __attribute__((ext_vector_type(8))) short bfrag8;
typedef __attribute__((ext_vector_type(4))) float ffrag4;

// RNE bf16: bit-exact vs __float2bfloat16 for finite inputs, 3 VALU ops.
__device__ __forceinline__ unsigned short f2b(float f) {
  uint32_t u; __builtin_memcpy(&u, &f, 4);
  u += 0x7fff + ((u >> 16) & 1);
  return (unsigned short)(u >> 16);
}

// ---- fusion-matrix diagonal: sdfm[b][d] = sqrt(sigmoid(x @ fmg_w[:,65d])) ----
__global__ void k_dfm(const float* __restrict__ hsi, const float* __restrict__ lidar,
                      const float* __restrict__ fmg_w, float* __restrict__ sdfm) {
  __shared__ float xc[128];
  int b = blockIdx.x, t = threadIdx.x;
  const float* src = (t < 64) ? hsi : lidar;
  int d = t & 63;
  const float* p = src + ((size_t)b * 64 + d) * NPATCH;
  float s = 0.f;
  for (int i = 0; i < NPATCH; ++i) s += p[i];
  xc[t] = s * (1.0f / 225.0f);
  __syncthreads();
  if (t < 64) {
    float acc = 0.f;
    const float* w = fmg_w + t * 65;       // column 65*t of [128,4096]
    for (int c = 0; c < 128; ++c) acc += xc[c] * w[c * 4096];
    float sg = 1.0f / (1.0f + expf(-acc));
    sdfm[b * 64 + t] = sqrtf(sg);
  }
}

// ---- build X[2B,226,64] (+ pos) and Xn = LN1_0(X); one wave per row ----
__global__ void k_build(const float* __restrict__ hsi,
                        const float* __restrict__ cls_h, const float* __restrict__ cls_l,
                        const float* __restrict__ pos_h, const float* __restrict__ pos_l,
                        const float* __restrict__ g, const float* __restrict__ bb,
                        float* __restrict__ X, uint16_t* __restrict__ Xn) {
  int r = blockIdx.x;                 // sb*226 + n
  int sb = r / NTOK, n = r - sb * NTOK;
  int s = sb >> 6, b = sb & 63;
  int d = threadIdx.x;                // 64 threads = 1 wave
  float v;
  if (n == 0) v = s ? cls_l[d] : cls_h[d];
  else        v = hsi[((size_t)b * 64 + d) * NPATCH + (n - 1)];
  v += (s ? pos_l : pos_h)[n * ND + d];
  X[(size_t)r * ND + d] = v;
  float sm = v, sq = v * v;
  #pragma unroll
  for (int o = 32; o; o >>= 1) { sm += __shfl_xor(sm, o); sq += __shfl_xor(sq, o); }
  float m = sm * (1.f / 64.f);
  float rs = rsqrtf(sq * (1.f / 64.f) - m * m + 1e-5f);
  Xn[(size_t)r * ND + d] = f2b((v - m) * rs * g[d] + bb[d]);
}

// ---- weight convert+transpose to bf16 [col][k] layouts, all layers ----
__global__ __launch_bounds__(256) void k_wconv(
    const float* __restrict__ qkv_w, const float* __restrict__ out_w,
    const float* __restrict__ ff_w1, const float* __restrict__ ff_w2,
    uint16_t* __restrict__ Wqv, uint16_t* __restrict__ Wo,
    uint16_t* __restrict__ W1, uint16_t* __restrict__ W2) {
  int i = blockIdx.x * 256 + threadIdx.x;   // grid covers 524288
  if (i < 262144) {
    int ly = i >> 16, rem = i & 65535, n = rem >> 6, k = rem & 63;
    int col = n + ((n >> 9) << 9);          // n<512 ? q col n : v col n+512
    Wqv[i] = f2b(qkv_w[((size_t)ly * 64 + k) * 1536 + col]);
  } else if (i < 393216) {
    int j = i - 262144;
    int ly = j >> 15, rem = j & 32767, n = rem >> 9, k = rem & 511;
    Wo[j] = f2b(out_w[((size_t)ly * 512 + k) * 64 + n]);
  } else if (i < 458752) {
    int j = i - 393216;
    int ly = j >> 14, rem = j & 16383, n = rem >> 6, k = rem & 63;
    W1[j] = f2b(ff_w1[((size_t)ly * 64 + k) * 256 + n]);
  } else {
    int j = i - 458752;
    int ly = j >> 14, rem = j & 16383, n = rem >> 8, k = rem & 255;
    W2[j] = f2b(ff_w2[((size_t)ly * 256 + k) * 64 + n]);
  }
}

// ---- fused QV-projection + MFMA attention (R10 structure; packed LDS stores) ----
// Phase 1: Q^T tiles via operand-swapped MFMA (A=Wq rows, B=Xn rows) -> lane
//          holds 4 consecutive d at fixed i -> ONE b64 write into swizzled qs.
//          V tiles in normal order -> 4 consecutive i at fixed d -> b64 into vt.
// Phase 2: unchanged (S = Qs Qs^T, raw-E softmax, PV, 1/l at store).
// LDS = 30720 (qs) + 31744 (vt) + 4096 (pb) = 66560 B -> 2 blocks/CU.
__global__ __launch_bounds__(256) void k_fattn(const uint16_t* __restrict__ Xn,
    const uint16_t* __restrict__ Wqv,   // [1024][64] this layer
    const float* __restrict__ sdfm, uint16_t* __restrict__ Og) {
  __shared__ __align__(16) uint16_t qs[240 * 64];
  __shared__ __align__(16) uint16_t vt[64 * VP];
  __shared__ __align__(16) uint16_t pb[4][512];
  int bh = blockIdx.x;
  int sb = bh >> 3, h = bh & 7;
  int t = threadIdx.x, w = t >> 6, l = t & 63;
  int quad = l >> 4, c = l & 15;
  const uint16_t* Xb = Xn + (size_t)sb * NTOK * ND;

  // per-lane Q-row scales: d = dt*16 + quad*4 + r
  float sfq[4][4];
  #pragma unroll
  for (int dt = 0; dt < 4; ++dt) {
    float4 sv = *(const float4*)(sdfm + (sb & 63) * 64 + dt * 16 + quad * 4);
    sfq[dt][0] = sv.x * 0.35355339059327373f;
    sfq[dt][1] = sv.y * 0.35355339059327373f;
    sfq[dt][2] = sv.z * 0.35355339059327373f;
    sfq[dt][3] = sv.w * 0.35355339059327373f;
  }

  // phase 1: Q^T and V for this head; packed b64 LDS stores
  for (int it = w; it < 15; it += 4) {
    int i0 = it * 16;
    int ri = i0 + c; if (ri > 225) ri = 225;
    bfrag8 a0 = *(const bfrag8*)(Xb + (size_t)ri * 64 + quad * 8);
    bfrag8 a1 = *(const bfrag8*)(Xb + (size_t)ri * 64 + 32 + quad * 8);
    int iw = i0 + c;                      // qs row this lane writes (<= 239)
    #pragma unroll
    for (int dt = 0; dt < 4; ++dt) {
      int nq = h * 64 + dt * 16 + c;
      bfrag8 bq0 = *(const bfrag8*)(Wqv + (size_t)nq * 64 + quad * 8);
      bfrag8 bq1 = *(const bfrag8*)(Wqv + (size_t)nq * 64 + 32 + quad * 8);
      // Q^T tile: D[d][i] = Wq^T · Xn^T (A = Wq rows, B = Xn rows)
      ffrag4 zq = {0.f, 0.f, 0.f, 0.f};
      zq = __builtin_amdgcn_mfma_f32_16x16x32_bf16(bq0, a0, zq, 0, 0, 0);
      zq = __builtin_amdgcn_mfma_f32_16x16x32_bf16(bq1, a1, zq, 0, 0, 0);
      // V tile: D[i][d] = Xn · Wv (normal order)
      bfrag8 bv0 = *(const bfrag8*)(Wqv + (size_t)(512 + nq) * 64 + quad * 8);
      bfrag8 bv1 = *(const bfrag8*)(Wqv + (size_t)(512 + nq) * 64 + 32 + quad * 8);
      ffrag4 zv = {0.f, 0.f, 0.f, 0.f};
      zv = __builtin_amdgcn_mfma_f32_16x16x32_bf16(a0, bv0, zv, 0, 0, 0);
      zv = __builtin_amdgcn_mfma_f32_16x16x32_bf16(a1, bv1, zv, 0, 0, 0);
      // qs packed write: element (iw, d=dt*16+quad*4+r), swizzled [i][d] layout
      ushort4 qp;
      qp.x = f2b(zq[0] * sfq[dt][0]);
      qp.y = f2b(zq[1] * sfq[dt][1]);
      qp.z = f2b(zq[2] * sfq[dt][2]);
      qp.w = f2b(zq[3] * sfq[dt][3]);
      int dchunk = dt * 2 + (quad >> 1);
      *(ushort4*)(qs + iw * 64 + ((dchunk ^ (iw & 7)) << 3) + (quad & 1) * 4) = qp;
      // vt packed write: element (d=dt*16+c, i=i0+quad*4+r)
      ushort4 vp;
      vp.x = f2b(zv[0]); vp.y = f2b(zv[1]); vp.z = f2b(zv[2]); vp.w = f2b(zv[3]);
      *(ushort4*)(vt + (dt * 16 + c) * VP + i0 + quad * 4) = vp;
    }
  }
  __syncthreads();

  uint16_t* pw = &pb[w][0];
  for (int it = w; it < 15; it += 4) {
    int i0 = it * 16;
    int ra = i0 + c, sa = ra & 7;
    bfrag8 a0 = *(const bfrag8*)(qs + ra * 64 + ((quad ^ sa) << 3));
    bfrag8 a1 = *(const bfrag8*)(qs + ra * 64 + (((quad + 4) ^ sa) << 3));
    ffrag4 acc[15];
    #pragma unroll
    for (int jt = 0; jt < 15; ++jt) {
      int rb = jt * 16 + c, sk = rb & 7;
      bfrag8 b0 = *(const bfrag8*)(qs + rb * 64 + ((quad ^ sk) << 3));
      bfrag8 b1 = *(const bfrag8*)(qs + rb * 64 + (((quad + 4) ^ sk) << 3));
      ffrag4 z = {0.f, 0.f, 0.f, 0.f};
      z = __builtin_amdgcn_mfma_f32_16x16x32_bf16(a0, b0, z, 0, 0, 0);
      z = __builtin_amdgcn_mfma_f32_16x16x32_bf16(a1, b1, z, 0, 0, 0);
      acc[jt] = z;
    }
    // softmax: store raw E = exp(S - m); 1/l applied at O store
    float rinv[4];
    #pragma unroll
    for (int r = 0; r < 4; ++r) {
      float m = -1e30f;
      #pragma unroll
      for (int jt = 0; jt < 15; ++jt) m = fmaxf(m, acc[jt][r]);
      #pragma unroll
      for (int o = 8; o; o >>= 1) m = fmaxf(m, __shfl_xor(m, o));
      float s = 0.f;
      #pragma unroll
      for (int jt = 0; jt < 15; ++jt) {
        float p = __expf(acc[jt][r] - m);
        if (jt == 14 && c >= 2) p = 0.f;   // j = 224+c >= 226 invalid (dup rows)
        acc[jt][r] = p;
        s += p;
      }
      #pragma unroll
      for (int o = 8; o; o >>= 1) s += __shfl_xor(s, o);
      rinv[r] = 1.f / s;
    }
    ffrag4 oa[4];
    #pragma unroll
    for (int dt = 0; dt < 4; ++dt) oa[dt] = (ffrag4){0.f, 0.f, 0.f, 0.f};
    for (int jc = 0; jc < 8; ++jc) {
      if (jc == 7) {
        *(uint64_t*)(pw + c * 32 + 16 + quad * 4) = 0ull;   // zero E cols 16..31
      }
      #pragma unroll
      for (int r = 0; r < 4; ++r) {
        int row = quad * 4 + r;
        pw[row * 32 + c] = f2b(acc[2 * jc][r]);
        if (jc < 7) pw[row * 32 + 16 + c] = f2b(acc[2 * jc + 1][r]);
      }
      bfrag8 pa = *(const bfrag8*)(pw + c * 32 + quad * 8);
      int j0 = jc * 32;
      #pragma unroll
      for (int dt = 0; dt < 4; ++dt) {
        bfrag8 vb;
        if (jc < 7)
          vb = *(const bfrag8*)(vt + (dt * 16 + c) * VP + j0 + quad * 8);
        else
          vb = *(const bfrag8*)(vt + (dt * 16 + c) * VP + 224 + (quad & 1) * 8);
        oa[dt] = __builtin_amdgcn_mfma_f32_16x16x32_bf16(pa, vb, oa[dt], 0, 0, 0);
      }
    }
    #pragma unroll
    for (int dt = 0; dt < 4; ++dt) {
      #pragma unroll
      for (int r = 0; r < 4; ++r) {
        int i = i0 + quad * 4 + r;
        if (i < NTOK)
          Og[((size_t)sb * NTOK + i) * NIN + h * DH + dt * 16 + c] =
              f2b(oa[dt][r] * rinv[r]);
      }
    }
  }
}

// ---- merged proj+FF: X += O@Wo+bo; LN2 (LDS); FF + residual; LN1-next ----
// Per-wave-exclusive 16-row tiles -> zero barriers. LDS = 9216 + 33792 = 43008 B.
__global__ __launch_bounds__(256) void k_pf(const uint16_t* __restrict__ Og,
    const uint16_t* __restrict__ Wot,   // [64][512] bf16
    const float* __restrict__ bo, float* __restrict__ X,
    const float* __restrict__ g2, const float* __restrict__ bb2,
    const uint16_t* __restrict__ W1t,   // [256][64] bf16
    const float* __restrict__ b1,
    const uint16_t* __restrict__ W2t,   // [64][256] bf16
    const float* __restrict__ b2,
    const float* __restrict__ gn, const float* __restrict__ bbn,
    uint16_t* __restrict__ XnOut) {
  __shared__ __align__(16) uint16_t xa2[64 * 72];      // 9216 B (pitch 72: even banks)
  __shared__ __align__(16) uint16_t ha[4][16 * 264];   // 33792 B per-wave h-tiles
  int t = threadIdx.x, w = t >> 6, l = t & 63;
  int quad = l >> 4, c = l & 15;
  int r0 = blockIdx.x * 64;

  // ---- proj part ----
  const uint16_t* orow = Og + (size_t)(r0 + w * 16 + c) * 512 + quad * 8;
  bfrag8 a[16];
  #pragma unroll
  for (int kc = 0; kc < 16; ++kc) a[kc] = *(const bfrag8*)(orow + kc * 32);
  ffrag4 acc[4];
  #pragma unroll
  for (int jt = 0; jt < 4; ++jt) acc[jt] = (ffrag4){0.f, 0.f, 0.f, 0.f};
  #pragma unroll
  for (int kc = 0; kc < 16; ++kc) {
    #pragma unroll
    for (int jt = 0; jt < 4; ++jt) {
      bfrag8 b = *(const bfrag8*)(Wot + (size_t)(jt * 16 + c) * 512 + kc * 32 + quad * 8);
      acc[jt] = __builtin_amdgcn_mfma_f32_16x16x32_bf16(a[kc], b, acc[jt], 0, 0, 0);
    }
  }
  float xv[4][4];
  #pragma unroll
  for (int jt = 0; jt < 4; ++jt) {
    float bv = bo[jt * 16 + c];
    #pragma unroll
    for (int r = 0; r < 4; ++r) {
      int il = w * 16 + quad * 4 + r;
      size_t idx = (size_t)(r0 + il) * 64 + jt * 16 + c;
      float v = X[idx] + acc[jt][r] + bv;
      X[idx] = v;
      xv[jt][r] = v;
    }
  }
  // LN2 -> xa2 (per-wave rows; no barrier needed)
  #pragma unroll
  for (int r = 0; r < 4; ++r) {
    float s = xv[0][r] + xv[1][r] + xv[2][r] + xv[3][r];
    float q = xv[0][r]*xv[0][r] + xv[1][r]*xv[1][r] + xv[2][r]*xv[2][r] + xv[3][r]*xv[3][r];
    #pragma unroll
    for (int o = 8; o; o >>= 1) { s += __shfl_xor(s, o); q += __shfl_xor(q, o); }
    float m = s * (1.f / 64.f);
    float rs = rsqrtf(q * (1.f / 64.f) - m * m + 1e-5f);
    int il = w * 16 + quad * 4 + r;
    #pragma unroll
    for (int jt = 0; jt < 4; ++jt) {
      int n = jt * 16 + c;
      xa2[il * 72 + n] = f2b((xv[jt][r] - m) * rs * g2[n] + bb2[n]);
    }
  }
  // ---- FF part (A from LDS xa2) ----
  const uint16_t* xrow = xa2 + (w * 16 + c) * 72;
  bfrag8 a0 = *(const bfrag8*)(xrow + quad * 8);
  bfrag8 a1 = *(const bfrag8*)(xrow + 32 + quad * 8);
  ffrag4 acc1[16];
  #pragma unroll
  for (int jt = 0; jt < 16; ++jt) {
    bfrag8 b0  = *(const bfrag8*)(W1t + (size_t)(jt * 16 + c) * 64 + quad * 8);
    bfrag8 b1f = *(const bfrag8*)(W1t + (size_t)(jt * 16 + c) * 64 + 32 + quad * 8);
    ffrag4 z = {0.f, 0.f, 0.f, 0.f};
    z = __builtin_amdgcn_mfma_f32_16x16x32_bf16(a0, b0, z, 0, 0, 0);
    z = __builtin_amdgcn_mfma_f32_16x16x32_bf16(a1, b1f, z, 0, 0, 0);
    acc1[jt] = z;
  }
  uint16_t* haw = &ha[w][0];
  #pragma unroll
  for (int jt = 0; jt < 16; ++jt) {
    float bv = b1[jt * 16 + c];
    #pragma unroll
    for (int r = 0; r < 4; ++r) {
      float z = acc1[jt][r] + bv;
      float hg = 0.5f * z * (1.f + erff(z * 0.7071067811865476f));
      haw[(quad * 4 + r) * 264 + jt * 16 + c] = f2b(hg);
    }
  }
  ffrag4 o2[4];
  #pragma unroll
  for (int jt = 0; jt < 4; ++jt) o2[jt] = (ffrag4){0.f, 0.f, 0.f, 0.f};
  #pragma unroll
  for (int kc = 0; kc < 8; ++kc) {
    bfrag8 pa = *(const bfrag8*)(haw + c * 264 + kc * 32 + quad * 8);
    #pragma unroll
    for (int jt = 0; jt < 4; ++jt) {
      bfrag8 vb = *(const bfrag8*)(W2t + (size_t)(jt * 16 + c) * 256 + kc * 32 + quad * 8);
      o2[jt] = __builtin_amdgcn_mfma_f32_16x16x32_bf16(pa, vb, o2[jt], 0, 0, 0);
    }
  }
  float yv[4][4];
  #pragma unroll
  for (int jt = 0; jt < 4; ++jt) {
    float bv = b2[jt * 16 + c];
    #pragma unroll
    for (int r = 0; r < 4; ++r) {
      int il = w * 16 + quad * 4 + r;
      size_t idx = (size_t)(r0 + il) * 64 + jt * 16 + c;
      float v = X[idx] + o2[jt][r] + bv;
      X[idx] = v;
      yv[jt][r] = v;
    }
  }
  #pragma unroll
  for (int r = 0; r < 4; ++r) {
    float s = yv[0][r] + yv[1][r] + yv[2][r] + yv[3][r];
    float q = yv[0][r]*yv[0][r] + yv[1][r]*yv[1][r] + yv[2][r]*yv[2][r] + yv[3][r]*yv[3][r];
    #pragma unroll
    for (int o = 8; o; o >>= 1) { s += __shfl_xor(s, o); q += __shfl_xor(q, o); }
    float m = s * (1.f / 64.f);
    float rs = rsqrtf(q * (1.f / 64.f) - m * m + 1e-5f);
    int il = w * 16 + quad * 4 + r;
    #pragma unroll
    for (int jt = 0; jt < 4; ++jt) {
      int n = jt * 16 + c;
      XnOut[(size_t)(r0 + il) * 64 + n] = f2b((yv[jt][r] - m) * rs * gn[n] + bbn[n]);
    }
  }
}

// ---- swap cls tokens between streams; refresh Xn (LN1 layer0) for those rows ----
__global__ void k_xchg(float* __restrict__ X, uint16_t* __restrict__ Xn,
                       const float* __restrict__ g, const float* __restrict__ bb) {
  int b = blockIdx.x, d = threadIdx.x;   // 64 blocks x 64 threads (1 wave)
  size_t i0 = (size_t)(b * NTOK) * ND + d;
  size_t i1 = (size_t)((64 + b) * NTOK) * ND + d;
  float a = X[i0], cc = X[i1];
  X[i0] = cc; X[i1] = a;
  float s0 = cc, q0 = cc * cc, s1 = a, q1 = a * a;
  #pragma unroll
  for (int o = 32; o; o >>= 1) {
    s0 += __shfl_xor(s0, o); q0 += __shfl_xor(q0, o);
    s1 += __shfl_xor(s1, o); q1 += __shfl_xor(q1, o);
  }
  float m0 = s0 * (1.f / 64.f), rs0 = rsqrtf(q0 * (1.f / 64.f) - m0 * m0 + 1e-5f);
  float m1 = s1 * (1.f / 64.f), rs1 = rsqrtf(q1 * (1.f / 64.f) - m1 * m1 + 1e-5f);
  Xn[i0] = f2b((cc - m0) * rs0 * g[d] + bb[d]);
  Xn[i1] = f2b((a - m1) * rs1 * g[d] + bb[d]);
}

// ---- final: out = h_cls + l_cls ----
__global__ void k_out(const float* __restrict__ X, float* __restrict__ out) {
  int i = blockIdx.x * 64 + threadIdx.x;
  int b = i >> 6, d = i & 63;
  out[i] = X[(size_t)b * NTOK * ND + d] + X[(size_t)(64 + b) * NTOK * ND + d];
}

extern "C" void kernel_launch(void* const* d_in, const int* in_sizes, int n_in,
                              void* d_out, int out_size, void* d_ws, size_t ws_size,
                              hipStream_t stream) {
  const float* hsi   = (const float*)d_in[0];
  const float* lidar = (const float*)d_in[1];
  const float* cls_h = (const float*)d_in[2];
  const float* cls_l = (const float*)d_in[3];
  const float* pos_h = (const float*)d_in[4];
  const float* pos_l = (const float*)d_in[5];
  const float* fmg_w = (const float*)d_in[6];
  const float* ln1_g = (const float*)d_in[7];
  const float* ln1_b = (const float*)d_in[8];
  const float* qkv_w = (const float*)d_in[9];
  const float* out_w = (const float*)d_in[10];
  const float* out_b = (const float*)d_in[11];
  const float* ln2_g = (const float*)d_in[12];
  const float* ln2_b = (const float*)d_in[13];
  const float* ff_w1 = (const float*)d_in[14];
  const float* ff_b1 = (const float*)d_in[15];
  const float* ff_w2 = (const float*)d_in[16];
  const float* ff_b2 = (const float*)d_in[17];

  char* ws = (char*)d_ws;
  float*    X    = (float*)ws;                       // 7,405,568 B
  float*    sdfm = (float*)(ws + 7405568);           // 16,384 B
  uint16_t* Xn   = (uint16_t*)(ws + 7421952);        // 3,702,784 B
  uint16_t* Og   = (uint16_t*)(ws + 11124736);       // 29,622,272 B
  uint16_t* Wqv  = (uint16_t*)(ws + 40747008);       // 524,288 B
  uint16_t* Wo   = (uint16_t*)(ws + 41271296);       // 262,144 B
  uint16_t* W1   = (uint16_t*)(ws + 41533440);       // 131,072 B
  uint16_t* W2   = (uint16_t*)(ws + 41664512);       // 131,072 B -> end 41,795,584

  k_wconv<<<2048, 256, 0, stream>>>(qkv_w, out_w, ff_w1, ff_w2, Wqv, Wo, W1, W2);
  k_dfm<<<NB, 128, 0, stream>>>(hsi, lidar, fmg_w, sdfm);
  k_build<<<NROWS, 64, 0, stream>>>(hsi, cls_h, cls_l, pos_h, pos_l,
                                    ln1_g, ln1_b, X, Xn);
  for (int pass = 0; pass < 2; ++pass) {
    for (int ly = 0; ly < NDEPTH; ++ly) {
      int nx = (ly + 1) & 3;   // next layer's LN1 params (harmless on final layer)
      k_fattn<<<NSB * NH, 256, 0, stream>>>(Xn, Wqv + (size_t)ly * 65536, sdfm, Og);
      k_pf<<<452, 256, 0, stream>>>(Og, Wo + (size_t)ly * 32768, out_b + ly * ND,
                                    X, ln2_g + ly * ND, ln2_b + ly * ND,
                                    W1 + (size_t)ly * 16384, ff_b1 + ly * NMLP,
                                    W2 + (size_t)ly * 16384, ff_b2 + ly * ND,
                                    ln1_g + nx * ND, ln1_b + nx * ND, Xn);
    }
    if (pass == 0) k_xchg<<<64, 64, 0, stream>>>(X, Xn, ln1_g, ln1_b);
  }
  k_out<<<64, 64, 0, stream>>>(X, (float*)d_out);
}

// Round 12
// 849.911 us; speedup vs baseline: 1.0118x; 1.0118x over previous
//
#include <hip/hip_runtime.h>
#include <hip/hip_bf16.h>
#include <cstdint>

#define NB 64        // batch
#define ND 64        // DIM
#define NH 8         // heads
#define DH 64        // dim_head
#define NIN 512      // inner
#define NMLP 256
#define NDEPTH 4
#define NPATCH 225
#define NTOK 226
#define NSB 128      // 2*B (both streams batched)
#define NROWS (NSB*NTOK)   // 28928

#define VP 240       // attention Vt LDS pitch (bf16 units) — R5/R10-validated

typedef __attribute__((ext_vector_type(8))) short bfrag8;
typedef __attribute__((ext_vector_type(4))) float ffrag4;

// RNE bf16: bit-exact vs __float2bfloat16 for finite inputs, 3 VALU ops.
__device__ __forceinline__ unsigned short f2b(float f) {
  uint32_t u; __builtin_memcpy(&u, &f, 4);
  u += 0x7fff + ((u >> 16) & 1);
  return (unsigned short)(u >> 16);
}

// ---- fusion-matrix diagonal: sdfm[b][d] = sqrt(sigmoid(x @ fmg_w[:,65d])) ----
__global__ void k_dfm(const float* __restrict__ hsi, const float* __restrict__ lidar,
                      const float* __restrict__ fmg_w, float* __restrict__ sdfm) {
  __shared__ float xc[128];
  int b = blockIdx.x, t = threadIdx.x;
  const float* src = (t < 64) ? hsi : lidar;
  int d = t & 63;
  const float* p = src + ((size_t)b * 64 + d) * NPATCH;
  float s = 0.f;
  for (int i = 0; i < NPATCH; ++i) s += p[i];
  xc[t] = s * (1.0f / 225.0f);
  __syncthreads();
  if (t < 64) {
    float acc = 0.f;
    const float* w = fmg_w + t * 65;       // column 65*t of [128,4096]
    for (int c = 0; c < 128; ++c) acc += xc[c] * w[c * 4096];
    float sg = 1.0f / (1.0f + expf(-acc));
    sdfm[b * 64 + t] = sqrtf(sg);
  }
}

// ---- build X[2B,226,64] (+ pos) and Xn = LN1_0(X); one wave per row ----
__global__ void k_build(const float* __restrict__ hsi,
                        const float* __restrict__ cls_h, const float* __restrict__ cls_l,
                        const float* __restrict__ pos_h, const float* __restrict__ pos_l,
                        const float* __restrict__ g, const float* __restrict__ bb,
                        float* __restrict__ X, uint16_t* __restrict__ Xn) {
  int r = blockIdx.x;                 // sb*226 + n
  int sb = r / NTOK, n = r - sb * NTOK;
  int s = sb >> 6, b = sb & 63;
  int d = threadIdx.x;                // 64 threads = 1 wave
  float v;
  if (n == 0) v = s ? cls_l[d] : cls_h[d];
  else        v = hsi[((size_t)b * 64 + d) * NPATCH + (n - 1)];
  v += (s ? pos_l : pos_h)[n * ND + d];
  X[(size_t)r * ND + d] = v;
  float sm = v, sq = v * v;
  #pragma unroll
  for (int o = 32; o; o >>= 1) { sm += __shfl_xor(sm, o); sq += __shfl_xor(sq, o); }
  float m = sm * (1.f / 64.f);
  float rs = rsqrtf(sq * (1.f / 64.f) - m * m + 1e-5f);
  Xn[(size_t)r * ND + d] = f2b((v - m) * rs * g[d] + bb[d]);
}

// ---- weight convert+transpose to bf16 [col][k] layouts, all layers ----
__global__ __launch_bounds__(256) void k_wconv(
    const float* __restrict__ qkv_w, const float* __restrict__ out_w,
    const float* __restrict__ ff_w1, const float* __restrict__ ff_w2,
    uint16_t* __restrict__ Wqv, uint16_t* __restrict__ Wo,
    uint16_t* __restrict__ W1, uint16_t* __restrict__ W2) {
  int i = blockIdx.x * 256 + threadIdx.x;   // grid covers 524288
  if (i < 262144) {
    int ly = i >> 16, rem = i & 65535, n = rem >> 6, k = rem & 63;
    int col = n + ((n >> 9) << 9);          // n<512 ? q col n : v col n+512
    Wqv[i] = f2b(qkv_w[((size_t)ly * 64 + k) * 1536 + col]);
  } else if (i < 393216) {
    int j = i - 262144;
    int ly = j >> 15, rem = j & 32767, n = rem >> 9, k = rem & 511;
    Wo[j] = f2b(out_w[((size_t)ly * 512 + k) * 64 + n]);
  } else if (i < 458752) {
    int j = i - 393216;
    int ly = j >> 14, rem = j & 16383, n = rem >> 6, k = rem & 63;
    W1[j] = f2b(ff_w1[((size_t)ly * 64 + k) * 256 + n]);
  } else {
    int j = i - 458752;
    int ly = j >> 14, rem = j & 16383, n = rem >> 8, k = rem & 255;
    W2[j] = f2b(ff_w2[((size_t)ly * 256 + k) * 64 + n]);
  }
}

// ---- fused QV-projection + MFMA attention (R10-proven version, verbatim) ----
__global__ __launch_bounds__(256) void k_fattn(const uint16_t* __restrict__ Xn,
    const uint16_t* __restrict__ Wqv,   // [1024][64] this layer
    const float* __restrict__ sdfm, uint16_t* __restrict__ Og) {
  __shared__ __align__(16) uint16_t qs[240 * 64];
  __shared__ __align__(16) uint16_t vt[64 * VP];
  __shared__ __align__(16) uint16_t pb[4][512];
  int bh = blockIdx.x;
  int sb = bh >> 3, h = bh & 7;
  int t = threadIdx.x, w = t >> 6, l = t & 63;
  int quad = l >> 4, c = l & 15;
  const uint16_t* Xb = Xn + (size_t)sb * NTOK * ND;

  float sf[4];
  #pragma unroll
  for (int dt = 0; dt < 4; ++dt)
    sf[dt] = sdfm[(sb & 63) * 64 + dt * 16 + c] * 0.35355339059327373f;  // sqrt(1/8)

  // phase 1: Q,V projection for this head
  for (int it = w; it < 15; it += 4) {
    int i0 = it * 16;
    int ri = i0 + c; if (ri > 225) ri = 225;
    bfrag8 a0 = *(const bfrag8*)(Xb + (size_t)ri * 64 + quad * 8);
    bfrag8 a1 = *(const bfrag8*)(Xb + (size_t)ri * 64 + 32 + quad * 8);
    #pragma unroll
    for (int dt = 0; dt < 4; ++dt) {
      int nq = h * 64 + dt * 16 + c;
      bfrag8 bq0 = *(const bfrag8*)(Wqv + (size_t)nq * 64 + quad * 8);
      bfrag8 bq1 = *(const bfrag8*)(Wqv + (size_t)nq * 64 + 32 + quad * 8);
      ffrag4 zq = {0.f, 0.f, 0.f, 0.f};
      zq = __builtin_amdgcn_mfma_f32_16x16x32_bf16(a0, bq0, zq, 0, 0, 0);
      zq = __builtin_amdgcn_mfma_f32_16x16x32_bf16(a1, bq1, zq, 0, 0, 0);
      bfrag8 bv0 = *(const bfrag8*)(Wqv + (size_t)(512 + nq) * 64 + quad * 8);
      bfrag8 bv1 = *(const bfrag8*)(Wqv + (size_t)(512 + nq) * 64 + 32 + quad * 8);
      ffrag4 zv = {0.f, 0.f, 0.f, 0.f};
      zv = __builtin_amdgcn_mfma_f32_16x16x32_bf16(a0, bv0, zv, 0, 0, 0);
      zv = __builtin_amdgcn_mfma_f32_16x16x32_bf16(a1, bv1, zv, 0, 0, 0);
      int d = dt * 16 + c;
      #pragma unroll
      for (int r = 0; r < 4; ++r) {
        int i = i0 + quad * 4 + r;
        qs[i * 64 + ((((d >> 3) ^ (i & 7))) << 3) + (d & 7)] = f2b(zq[r] * sf[dt]);
        vt[d * VP + i] = f2b(zv[r]);
      }
    }
  }
  __syncthreads();

  uint16_t* pw = &pb[w][0];
  for (int it = w; it < 15; it += 4) {
    int i0 = it * 16;
    int ra = i0 + c, sa = ra & 7;
    bfrag8 a0 = *(const bfrag8*)(qs + ra * 64 + ((quad ^ sa) << 3));
    bfrag8 a1 = *(const bfrag8*)(qs + ra * 64 + (((quad + 4) ^ sa) << 3));
    ffrag4 acc[15];
    #pragma unroll
    for (int jt = 0; jt < 15; ++jt) {
      int rb = jt * 16 + c, sk = rb & 7;
      bfrag8 b0 = *(const bfrag8*)(qs + rb * 64 + ((quad ^ sk) << 3));
      bfrag8 b1 = *(const bfrag8*)(qs + rb * 64 + (((quad + 4) ^ sk) << 3));
      ffrag4 z = {0.f, 0.f, 0.f, 0.f};
      z = __builtin_amdgcn_mfma_f32_16x16x32_bf16(a0, b0, z, 0, 0, 0);
      z = __builtin_amdgcn_mfma_f32_16x16x32_bf16(a1, b1, z, 0, 0, 0);
      acc[jt] = z;
    }
    // softmax: store raw E = exp(S - m); 1/l applied at O store
    float rinv[4];
    #pragma unroll
    for (int r = 0; r < 4; ++r) {
      float m = -1e30f;
      #pragma unroll
      for (int jt = 0; jt < 15; ++jt) m = fmaxf(m, acc[jt][r]);
      #pragma unroll
      for (int o = 8; o; o >>= 1) m = fmaxf(m, __shfl_xor(m, o));
      float s = 0.f;
      #pragma unroll
      for (int jt = 0; jt < 15; ++jt) {
        float p = __expf(acc[jt][r] - m);
        if (jt == 14 && c >= 2) p = 0.f;   // j = 224+c >= 226 invalid (dup rows)
        acc[jt][r] = p;
        s += p;
      }
      #pragma unroll
      for (int o = 8; o; o >>= 1) s += __shfl_xor(s, o);
      rinv[r] = 1.f / s;
    }
    ffrag4 oa[4];
    #pragma unroll
    for (int dt = 0; dt < 4; ++dt) oa[dt] = (ffrag4){0.f, 0.f, 0.f, 0.f};
    for (int jc = 0; jc < 8; ++jc) {
      if (jc == 7) {
        *(uint64_t*)(pw + c * 32 + 16 + quad * 4) = 0ull;   // zero E cols 16..31
      }
      #pragma unroll
      for (int r = 0; r < 4; ++r) {
        int row = quad * 4 + r;
        pw[row * 32 + c] = f2b(acc[2 * jc][r]);
        if (jc < 7) pw[row * 32 + 16 + c] = f2b(acc[2 * jc + 1][r]);
      }
      bfrag8 pa = *(const bfrag8*)(pw + c * 32 + quad * 8);
      int j0 = jc * 32;
      #pragma unroll
      for (int dt = 0; dt < 4; ++dt) {
        bfrag8 vb;
        if (jc < 7)
          vb = *(const bfrag8*)(vt + (dt * 16 + c) * VP + j0 + quad * 8);
        else
          vb = *(const bfrag8*)(vt + (dt * 16 + c) * VP + 224 + (quad & 1) * 8);
        oa[dt] = __builtin_amdgcn_mfma_f32_16x16x32_bf16(pa, vb, oa[dt], 0, 0, 0);
      }
    }
    #pragma unroll
    for (int dt = 0; dt < 4; ++dt) {
      #pragma unroll
      for (int r = 0; r < 4; ++r) {
        int i = i0 + quad * 4 + r;
        if (i < NTOK)
          Og[((size_t)sb * NTOK + i) * NIN + h * DH + dt * 16 + c] =
              f2b(oa[dt][r] * rinv[r]);
      }
    }
  }
}

// ---- merged proj+FF, ONE WAVE per 16-row tile (grid 1808) ----
// R10 k_pf per-wave code with w removed; LDS 10752 B/block; no barriers.
// Fix for R10's grid-starvation: 452 blocks (1.77/CU) -> 1808 (7/CU).
__global__ __launch_bounds__(64) void k_pf(const uint16_t* __restrict__ Og,
    const uint16_t* __restrict__ Wot,   // [64][512] bf16
    const float* __restrict__ bo, float* __restrict__ X,
    const float* __restrict__ g2, const float* __restrict__ bb2,
    const uint16_t* __restrict__ W1t,   // [256][64] bf16
    const float* __restrict__ b1,
    const uint16_t* __restrict__ W2t,   // [64][256] bf16
    const float* __restrict__ b2,
    const float* __restrict__ gn, const float* __restrict__ bbn,
    uint16_t* __restrict__ XnOut) {
  __shared__ __align__(16) uint16_t xa2[16 * 72];    // 2304 B
  __shared__ __align__(16) uint16_t ha[16 * 264];    // 8448 B
  int t = threadIdx.x;                 // 64 = 1 wave
  int quad = t >> 4, c = t & 15;
  int r0 = blockIdx.x * 16;

  // ---- proj part ----
  const uint16_t* orow = Og + (size_t)(r0 + c) * 512 + quad * 8;
  bfrag8 a[16];
  #pragma unroll
  for (int kc = 0; kc < 16; ++kc) a[kc] = *(const bfrag8*)(orow + kc * 32);
  ffrag4 acc[4];
  #pragma unroll
  for (int jt = 0; jt < 4; ++jt) acc[jt] = (ffrag4){0.f, 0.f, 0.f, 0.f};
  #pragma unroll
  for (int kc = 0; kc < 16; ++kc) {
    #pragma unroll
    for (int jt = 0; jt < 4; ++jt) {
      bfrag8 b = *(const bfrag8*)(Wot + (size_t)(jt * 16 + c) * 512 + kc * 32 + quad * 8);
      acc[jt] = __builtin_amdgcn_mfma_f32_16x16x32_bf16(a[kc], b, acc[jt], 0, 0, 0);
    }
  }
  float xv[4][4];
  #pragma unroll
  for (int jt = 0; jt < 4; ++jt) {
    float bv = bo[jt * 16 + c];
    #pragma unroll
    for (int r = 0; r < 4; ++r) {
      int il = quad * 4 + r;
      size_t idx = (size_t)(r0 + il) * 64 + jt * 16 + c;
      float v = X[idx] + acc[jt][r] + bv;
      X[idx] = v;
      xv[jt][r] = v;
    }
  }
  // LN2 -> xa2 (single wave; ds ordering within wave is program-order, no barrier)
  #pragma unroll
  for (int r = 0; r < 4; ++r) {
    float s = xv[0][r] + xv[1][r] + xv[2][r] + xv[3][r];
    float q = xv[0][r]*xv[0][r] + xv[1][r]*xv[1][r] + xv[2][r]*xv[2][r] + xv[3][r]*xv[3][r];
    #pragma unroll
    for (int o = 8; o; o >>= 1) { s += __shfl_xor(s, o); q += __shfl_xor(q, o); }
    float m = s * (1.f / 64.f);
    float rs = rsqrtf(q * (1.f / 64.f) - m * m + 1e-5f);
    int il = quad * 4 + r;
    #pragma unroll
    for (int jt = 0; jt < 4; ++jt) {
      int n = jt * 16 + c;
      xa2[il * 72 + n] = f2b((xv[jt][r] - m) * rs * g2[n] + bb2[n]);
    }
  }
  // ---- FF part (A from LDS xa2) ----
  const uint16_t* xrow = xa2 + c * 72;
  bfrag8 a0 = *(const bfrag8*)(xrow + quad * 8);
  bfrag8 a1 = *(const bfrag8*)(xrow + 32 + quad * 8);
  ffrag4 acc1[16];
  #pragma unroll
  for (int jt = 0; jt < 16; ++jt) {
    bfrag8 b0  = *(const bfrag8*)(W1t + (size_t)(jt * 16 + c) * 64 + quad * 8);
    bfrag8 b1f = *(const bfrag8*)(W1t + (size_t)(jt * 16 + c) * 64 + 32 + quad * 8);
    ffrag4 z = {0.f, 0.f, 0.f, 0.f};
    z = __builtin_amdgcn_mfma_f32_16x16x32_bf16(a0, b0, z, 0, 0, 0);
    z = __builtin_amdgcn_mfma_f32_16x16x32_bf16(a1, b1f, z, 0, 0, 0);
    acc1[jt] = z;
  }
  #pragma unroll
  for (int jt = 0; jt < 16; ++jt) {
    float bv = b1[jt * 16 + c];
    #pragma unroll
    for (int r = 0; r < 4; ++r) {
      float z = acc1[jt][r] + bv;
      float hg = 0.5f * z * (1.f + erff(z * 0.7071067811865476f));
      ha[(quad * 4 + r) * 264 + jt * 16 + c] = f2b(hg);
    }
  }
  ffrag4 o2[4];
  #pragma unroll
  for (int jt = 0; jt < 4; ++jt) o2[jt] = (ffrag4){0.f, 0.f, 0.f, 0.f};
  #pragma unroll
  for (int kc = 0; kc < 8; ++kc) {
    bfrag8 pa = *(const bfrag8*)(ha + c * 264 + kc * 32 + quad * 8);
    #pragma unroll
    for (int jt = 0; jt < 4; ++jt) {
      bfrag8 vb = *(const bfrag8*)(W2t + (size_t)(jt * 16 + c) * 256 + kc * 32 + quad * 8);
      o2[jt] = __builtin_amdgcn_mfma_f32_16x16x32_bf16(pa, vb, o2[jt], 0, 0, 0);
    }
  }
  float yv[4][4];
  #pragma unroll
  for (int jt = 0; jt < 4; ++jt) {
    float bv = b2[jt * 16 + c];
    #pragma unroll
    for (int r = 0; r < 4; ++r) {
      int il = quad * 4 + r;
      size_t idx = (size_t)(r0 + il) * 64 + jt * 16 + c;
      float v = X[idx] + o2[jt][r] + bv;
      X[idx] = v;
      yv[jt][r] = v;
    }
  }
  #pragma unroll
  for (int r = 0; r < 4; ++r) {
    float s = yv[0][r] + yv[1][r] + yv[2][r] + yv[3][r];
    float q = yv[0][r]*yv[0][r] + yv[1][r]*yv[1][r] + yv[2][r]*yv[2][r] + yv[3][r]*yv[3][r];
    #pragma unroll
    for (int o = 8; o; o >>= 1) { s += __shfl_xor(s, o); q += __shfl_xor(q, o); }
    float m = s * (1.f / 64.f);
    float rs = rsqrtf(q * (1.f / 64.f) - m * m + 1e-5f);
    int il = quad * 4 + r;
    #pragma unroll
    for (int jt = 0; jt < 4; ++jt) {
      int n = jt * 16 + c;
      XnOut[(size_t)(r0 + il) * 64 + n] = f2b((yv[jt][r] - m) * rs * gn[n] + bbn[n]);
    }
  }
}

// ---- swap cls tokens between streams; refresh Xn (LN1 layer0) for those rows ----
__global__ void k_xchg(float* __restrict__ X, uint16_t* __restrict__ Xn,
                       const float* __restrict__ g, const float* __restrict__ bb) {
  int b = blockIdx.x, d = threadIdx.x;   // 64 blocks x 64 threads (1 wave)
  size_t i0 = (size_t)(b * NTOK) * ND + d;
  size_t i1 = (size_t)((64 + b) * NTOK) * ND + d;
  float a = X[i0], cc = X[i1];
  X[i0] = cc; X[i1] = a;
  float s0 = cc, q0 = cc * cc, s1 = a, q1 = a * a;
  #pragma unroll
  for (int o = 32; o; o >>= 1) {
    s0 += __shfl_xor(s0, o); q0 += __shfl_xor(q0, o);
    s1 += __shfl_xor(s1, o); q1 += __shfl_xor(q1, o);
  }
  float m0 = s0 * (1.f / 64.f), rs0 = rsqrtf(q0 * (1.f / 64.f) - m0 * m0 + 1e-5f);
  float m1 = s1 * (1.f / 64.f), rs1 = rsqrtf(q1 * (1.f / 64.f) - m1 * m1 + 1e-5f);
  Xn[i0] = f2b((cc - m0) * rs0 * g[d] + bb[d]);
  Xn[i1] = f2b((a - m1) * rs1 * g[d] + bb[d]);
}

// ---- final: out = h_cls + l_cls ----
__global__ void k_out(const float* __restrict__ X, float* __restrict__ out) {
  int i = blockIdx.x * 64 + threadIdx.x;
  int b = i >> 6, d = i & 63;
  out[i] = X[(size_t)b * NTOK * ND + d] + X[(size_t)(64 + b) * NTOK * ND + d];
}

extern "C" void kernel_launch(void* const* d_in, const int* in_sizes, int n_in,
                              void* d_out, int out_size, void* d_ws, size_t ws_size,
                              hipStream_t stream) {
  const float* hsi   = (const float*)d_in[0];
  const float* lidar = (const float*)d_in[1];
  const float* cls_h = (const float*)d_in[2];
  const float* cls_l = (const float*)d_in[3];
  const float* pos_h = (const float*)d_in[4];
  const float* pos_l = (const float*)d_in[5];
  const float* fmg_w = (const float*)d_in[6];
  const float* ln1_g = (const float*)d_in[7];
  const float* ln1_b = (const float*)d_in[8];
  const float* qkv_w = (const float*)d_in[9];
  const float* out_w = (const float*)d_in[10];
  const float* out_b = (const float*)d_in[11];
  const float* ln2_g = (const float*)d_in[12];
  const float* ln2_b = (const float*)d_in[13];
  const float* ff_w1 = (const float*)d_in[14];
  const float* ff_b1 = (const float*)d_in[15];
  const float* ff_w2 = (const float*)d_in[16];
  const float* ff_b2 = (const float*)d_in[17];

  char* ws = (char*)d_ws;
  float*    X    = (float*)ws;                       // 7,405,568 B
  float*    sdfm = (float*)(ws + 7405568);           // 16,384 B
  uint16_t* Xn   = (uint16_t*)(ws + 7421952);        // 3,702,784 B
  uint16_t* Og   = (uint16_t*)(ws + 11124736);       // 29,622,272 B
  uint16_t* Wqv  = (uint16_t*)(ws + 40747008);       // 524,288 B
  uint16_t* Wo   = (uint16_t*)(ws + 41271296);       // 262,144 B
  uint16_t* W1   = (uint16_t*)(ws + 41533440);       // 131,072 B
  uint16_t* W2   = (uint16_t*)(ws + 41664512);       // 131,072 B -> end 41,795,584

  k_wconv<<<2048, 256, 0, stream>>>(qkv_w, out_w, ff_w1, ff_w2, Wqv, Wo, W1, W2);
  k_dfm<<<NB, 128, 0, stream>>>(hsi, lidar, fmg_w, sdfm);
  k_build<<<NROWS, 64, 0, stream>>>(hsi, cls_h, cls_l, pos_h, pos_l,
                                    ln1_g, ln1_b, X, Xn);
  for (int pass = 0; pass < 2; ++pass) {
    for (int ly = 0; ly < NDEPTH; ++ly) {
      int nx = (ly + 1) & 3;   // next layer's LN1 params (harmless on final layer)
      k_fattn<<<NSB * NH, 256, 0, stream>>>(Xn, Wqv + (size_t)ly * 65536, sdfm, Og);
      k_pf<<<NROWS / 16, 64, 0, stream>>>(Og, Wo + (size_t)ly * 32768, out_b + ly * ND,
                                          X, ln2_g + ly * ND, ln2_b + ly * ND,
                                          W1 + (size_t)ly * 16384, ff_b1 + ly * NMLP,
                                          W2 + (size_t)ly * 16384, ff_b2 + ly * ND,
                                          ln1_g + nx * ND, ln1_b + nx * ND, Xn);
    }
    if (pass == 0) k_xchg<<<64, 64, 0, stream>>>(X, Xn, ln1_g, ln1_b);
  }
  k_out<<<64, 64, 0, stream>>>(X, (float*)d_out);
}

// Round 13
// 810.687 us; speedup vs baseline: 1.0608x; 1.0484x over previous
//
#include <hip/hip_runtime.h>
#include <hip/hip_bf16.h>
#include <cstdint>

#define NB 64        // batch
#define ND 64        // DIM
#define NH 8         // heads
#define DH 64        // dim_head
#define NIN 512      // inner
#define NMLP 256
#define NDEPTH 4
#define NPATCH 225
#define NTOK 226
#define NSB 128      // 2*B (both streams batched)
#define NROWS (NSB*NTOK)   // 28928

#define VP 240       // attention Vt LDS pitch (bf16 units) — R5/R10-validated

typedef __attribute__((ext_vector_type(8))) short bfrag8;
typedef __attribute__((ext_vector_type(4))) float ffrag4;

// RNE bf16: bit-exact vs __float2bfloat16 for finite inputs, 3 VALU ops.
__device__ __forceinline__ unsigned short f2b(float f) {
  uint32_t u; __builtin_memcpy(&u, &f, 4);
  u += 0x7fff + ((u >> 16) & 1);
  return (unsigned short)(u >> 16);
}

// ---- fusion-matrix diagonal: sdfm[b][d] = sqrt(sigmoid(x @ fmg_w[:,65d])) ----
__global__ void k_dfm(const float* __restrict__ hsi, const float* __restrict__ lidar,
                      const float* __restrict__ fmg_w, float* __restrict__ sdfm) {
  __shared__ float xc[128];
  int b = blockIdx.x, t = threadIdx.x;
  const float* src = (t < 64) ? hsi : lidar;
  int d = t & 63;
  const float* p = src + ((size_t)b * 64 + d) * NPATCH;
  float s = 0.f;
  for (int i = 0; i < NPATCH; ++i) s += p[i];
  xc[t] = s * (1.0f / 225.0f);
  __syncthreads();
  if (t < 64) {
    float acc = 0.f;
    const float* w = fmg_w + t * 65;       // column 65*t of [128,4096]
    for (int c = 0; c < 128; ++c) acc += xc[c] * w[c * 4096];
    float sg = 1.0f / (1.0f + expf(-acc));
    sdfm[b * 64 + t] = sqrtf(sg);
  }
}

// ---- build X[2B,226,64] (+ pos) and Xn = LN1_0(X); one wave per row ----
__global__ void k_build(const float* __restrict__ hsi,
                        const float* __restrict__ cls_h, const float* __restrict__ cls_l,
                        const float* __restrict__ pos_h, const float* __restrict__ pos_l,
                        const float* __restrict__ g, const float* __restrict__ bb,
                        float* __restrict__ X, uint16_t* __restrict__ Xn) {
  int r = blockIdx.x;                 // sb*226 + n
  int sb = r / NTOK, n = r - sb * NTOK;
  int s = sb >> 6, b = sb & 63;
  int d = threadIdx.x;                // 64 threads = 1 wave
  float v;
  if (n == 0) v = s ? cls_l[d] : cls_h[d];
  else        v = hsi[((size_t)b * 64 + d) * NPATCH + (n - 1)];
  v += (s ? pos_l : pos_h)[n * ND + d];
  X[(size_t)r * ND + d] = v;
  float sm = v, sq = v * v;
  #pragma unroll
  for (int o = 32; o; o >>= 1) { sm += __shfl_xor(sm, o); sq += __shfl_xor(sq, o); }
  float m = sm * (1.f / 64.f);
  float rs = rsqrtf(sq * (1.f / 64.f) - m * m + 1e-5f);
  Xn[(size_t)r * ND + d] = f2b((v - m) * rs * g[d] + bb[d]);
}

// ---- weight convert+transpose to bf16 [col][k] layouts, all layers ----
__global__ __launch_bounds__(256) void k_wconv(
    const float* __restrict__ qkv_w, const float* __restrict__ out_w,
    const float* __restrict__ ff_w1, const float* __restrict__ ff_w2,
    uint16_t* __restrict__ Wqv, uint16_t* __restrict__ Wo,
    uint16_t* __restrict__ W1, uint16_t* __restrict__ W2) {
  int i = blockIdx.x * 256 + threadIdx.x;   // grid covers 524288
  if (i < 262144) {
    int ly = i >> 16, rem = i & 65535, n = rem >> 6, k = rem & 63;
    int col = n + ((n >> 9) << 9);          // n<512 ? q col n : v col n+512
    Wqv[i] = f2b(qkv_w[((size_t)ly * 64 + k) * 1536 + col]);
  } else if (i < 393216) {
    int j = i - 262144;
    int ly = j >> 15, rem = j & 32767, n = rem >> 9, k = rem & 511;
    Wo[j] = f2b(out_w[((size_t)ly * 512 + k) * 64 + n]);
  } else if (i < 458752) {
    int j = i - 393216;
    int ly = j >> 14, rem = j & 16383, n = rem >> 6, k = rem & 63;
    W1[j] = f2b(ff_w1[((size_t)ly * 64 + k) * 256 + n]);
  } else {
    int j = i - 458752;
    int ly = j >> 14, rem = j & 16383, n = rem >> 8, k = rem & 255;
    W2[j] = f2b(ff_w2[((size_t)ly * 256 + k) * 64 + n]);
  }
}

// ---- fused QV-projection + MFMA attention: 8 waves/block for 4 waves/SIMD ----
// R10/R12 logic with the i-tile loop split across 8 waves (it += 8) instead of 4.
// LDS = 30720 (qs) + 30720 (vt) + 8192 (pb) = 69632 B -> 2 blocks/CU -> 16 waves/CU.
__global__ __launch_bounds__(512) void k_fattn(const uint16_t* __restrict__ Xn,
    const uint16_t* __restrict__ Wqv,   // [1024][64] this layer
    const float* __restrict__ sdfm, uint16_t* __restrict__ Og) {
  __shared__ __align__(16) uint16_t qs[240 * 64];
  __shared__ __align__(16) uint16_t vt[64 * VP];
  __shared__ __align__(16) uint16_t pb[8][512];
  int bh = blockIdx.x;
  int sb = bh >> 3, h = bh & 7;
  int t = threadIdx.x, w = t >> 6, l = t & 63;
  int quad = l >> 4, c = l & 15;
  const uint16_t* Xb = Xn + (size_t)sb * NTOK * ND;

  float sf[4];
  #pragma unroll
  for (int dt = 0; dt < 4; ++dt)
    sf[dt] = sdfm[(sb & 63) * 64 + dt * 16 + c] * 0.35355339059327373f;  // sqrt(1/8)

  // phase 1: Q,V projection for this head (8-way wave split)
  for (int it = w; it < 15; it += 8) {
    int i0 = it * 16;
    int ri = i0 + c; if (ri > 225) ri = 225;
    bfrag8 a0 = *(const bfrag8*)(Xb + (size_t)ri * 64 + quad * 8);
    bfrag8 a1 = *(const bfrag8*)(Xb + (size_t)ri * 64 + 32 + quad * 8);
    #pragma unroll
    for (int dt = 0; dt < 4; ++dt) {
      int nq = h * 64 + dt * 16 + c;
      bfrag8 bq0 = *(const bfrag8*)(Wqv + (size_t)nq * 64 + quad * 8);
      bfrag8 bq1 = *(const bfrag8*)(Wqv + (size_t)nq * 64 + 32 + quad * 8);
      ffrag4 zq = {0.f, 0.f, 0.f, 0.f};
      zq = __builtin_amdgcn_mfma_f32_16x16x32_bf16(a0, bq0, zq, 0, 0, 0);
      zq = __builtin_amdgcn_mfma_f32_16x16x32_bf16(a1, bq1, zq, 0, 0, 0);
      bfrag8 bv0 = *(const bfrag8*)(Wqv + (size_t)(512 + nq) * 64 + quad * 8);
      bfrag8 bv1 = *(const bfrag8*)(Wqv + (size_t)(512 + nq) * 64 + 32 + quad * 8);
      ffrag4 zv = {0.f, 0.f, 0.f, 0.f};
      zv = __builtin_amdgcn_mfma_f32_16x16x32_bf16(a0, bv0, zv, 0, 0, 0);
      zv = __builtin_amdgcn_mfma_f32_16x16x32_bf16(a1, bv1, zv, 0, 0, 0);
      int d = dt * 16 + c;
      #pragma unroll
      for (int r = 0; r < 4; ++r) {
        int i = i0 + quad * 4 + r;
        qs[i * 64 + ((((d >> 3) ^ (i & 7))) << 3) + (d & 7)] = f2b(zq[r] * sf[dt]);
        vt[d * VP + i] = f2b(zv[r]);
      }
    }
  }
  __syncthreads();

  uint16_t* pw = &pb[w][0];
  for (int it = w; it < 15; it += 8) {
    int i0 = it * 16;
    int ra = i0 + c, sa = ra & 7;
    bfrag8 a0 = *(const bfrag8*)(qs + ra * 64 + ((quad ^ sa) << 3));
    bfrag8 a1 = *(const bfrag8*)(qs + ra * 64 + (((quad + 4) ^ sa) << 3));
    ffrag4 acc[15];
    #pragma unroll
    for (int jt = 0; jt < 15; ++jt) {
      int rb = jt * 16 + c, sk = rb & 7;
      bfrag8 b0 = *(const bfrag8*)(qs + rb * 64 + ((quad ^ sk) << 3));
      bfrag8 b1 = *(const bfrag8*)(qs + rb * 64 + (((quad + 4) ^ sk) << 3));
      ffrag4 z = {0.f, 0.f, 0.f, 0.f};
      z = __builtin_amdgcn_mfma_f32_16x16x32_bf16(a0, b0, z, 0, 0, 0);
      z = __builtin_amdgcn_mfma_f32_16x16x32_bf16(a1, b1, z, 0, 0, 0);
      acc[jt] = z;
    }
    // softmax: store raw E = exp(S - m); 1/l applied at O store
    float rinv[4];
    #pragma unroll
    for (int r = 0; r < 4; ++r) {
      float m = -1e30f;
      #pragma unroll
      for (int jt = 0; jt < 15; ++jt) m = fmaxf(m, acc[jt][r]);
      #pragma unroll
      for (int o = 8; o; o >>= 1) m = fmaxf(m, __shfl_xor(m, o));
      float s = 0.f;
      #pragma unroll
      for (int jt = 0; jt < 15; ++jt) {
        float p = __expf(acc[jt][r] - m);
        if (jt == 14 && c >= 2) p = 0.f;   // j = 224+c >= 226 invalid (dup rows)
        acc[jt][r] = p;
        s += p;
      }
      #pragma unroll
      for (int o = 8; o; o >>= 1) s += __shfl_xor(s, o);
      rinv[r] = 1.f / s;
    }
    ffrag4 oa[4];
    #pragma unroll
    for (int dt = 0; dt < 4; ++dt) oa[dt] = (ffrag4){0.f, 0.f, 0.f, 0.f};
    for (int jc = 0; jc < 8; ++jc) {
      if (jc == 7) {
        *(uint64_t*)(pw + c * 32 + 16 + quad * 4) = 0ull;   // zero E cols 16..31
      }
      #pragma unroll
      for (int r = 0; r < 4; ++r) {
        int row = quad * 4 + r;
        pw[row * 32 + c] = f2b(acc[2 * jc][r]);
        if (jc < 7) pw[row * 32 + 16 + c] = f2b(acc[2 * jc + 1][r]);
      }
      bfrag8 pa = *(const bfrag8*)(pw + c * 32 + quad * 8);
      int j0 = jc * 32;
      #pragma unroll
      for (int dt = 0; dt < 4; ++dt) {
        bfrag8 vb;
        if (jc < 7)
          vb = *(const bfrag8*)(vt + (dt * 16 + c) * VP + j0 + quad * 8);
        else
          vb = *(const bfrag8*)(vt + (dt * 16 + c) * VP + 224 + (quad & 1) * 8);
        oa[dt] = __builtin_amdgcn_mfma_f32_16x16x32_bf16(pa, vb, oa[dt], 0, 0, 0);
      }
    }
    #pragma unroll
    for (int dt = 0; dt < 4; ++dt) {
      #pragma unroll
      for (int r = 0; r < 4; ++r) {
        int i = i0 + quad * 4 + r;
        if (i < NTOK)
          Og[((size_t)sb * NTOK + i) * NIN + h * DH + dt * 16 + c] =
              f2b(oa[dt][r] * rinv[r]);
      }
    }
  }
}

// ---- merged proj+FF, one wave per 16-row tile (R12 version, unchanged) ----
__global__ __launch_bounds__(64) void k_pf(const uint16_t* __restrict__ Og,
    const uint16_t* __restrict__ Wot,   // [64][512] bf16
    const float* __restrict__ bo, float* __restrict__ X,
    const float* __restrict__ g2, const float* __restrict__ bb2,
    const uint16_t* __restrict__ W1t,   // [256][64] bf16
    const float* __restrict__ b1,
    const uint16_t* __restrict__ W2t,   // [64][256] bf16
    const float* __restrict__ b2,
    const float* __restrict__ gn, const float* __restrict__ bbn,
    uint16_t* __restrict__ XnOut) {
  __shared__ __align__(16) uint16_t xa2[16 * 72];    // 2304 B
  __shared__ __align__(16) uint16_t ha[16 * 264];    // 8448 B
  int t = threadIdx.x;                 // 64 = 1 wave
  int quad = t >> 4, c = t & 15;
  int r0 = blockIdx.x * 16;

  // ---- proj part ----
  const uint16_t* orow = Og + (size_t)(r0 + c) * 512 + quad * 8;
  bfrag8 a[16];
  #pragma unroll
  for (int kc = 0; kc < 16; ++kc) a[kc] = *(const bfrag8*)(orow + kc * 32);
  ffrag4 acc[4];
  #pragma unroll
  for (int jt = 0; jt < 4; ++jt) acc[jt] = (ffrag4){0.f, 0.f, 0.f, 0.f};
  #pragma unroll
  for (int kc = 0; kc < 16; ++kc) {
    #pragma unroll
    for (int jt = 0; jt < 4; ++jt) {
      bfrag8 b = *(const bfrag8*)(Wot + (size_t)(jt * 16 + c) * 512 + kc * 32 + quad * 8);
      acc[jt] = __builtin_amdgcn_mfma_f32_16x16x32_bf16(a[kc], b, acc[jt], 0, 0, 0);
    }
  }
  float xv[4][4];
  #pragma unroll
  for (int jt = 0; jt < 4; ++jt) {
    float bv = bo[jt * 16 + c];
    #pragma unroll
    for (int r = 0; r < 4; ++r) {
      int il = quad * 4 + r;
      size_t idx = (size_t)(r0 + il) * 64 + jt * 16 + c;
      float v = X[idx] + acc[jt][r] + bv;
      X[idx] = v;
      xv[jt][r] = v;
    }
  }
  // LN2 -> xa2 (single wave; program-order LDS, no barrier)
  #pragma unroll
  for (int r = 0; r < 4; ++r) {
    float s = xv[0][r] + xv[1][r] + xv[2][r] + xv[3][r];
    float q = xv[0][r]*xv[0][r] + xv[1][r]*xv[1][r] + xv[2][r]*xv[2][r] + xv[3][r]*xv[3][r];
    #pragma unroll
    for (int o = 8; o; o >>= 1) { s += __shfl_xor(s, o); q += __shfl_xor(q, o); }
    float m = s * (1.f / 64.f);
    float rs = rsqrtf(q * (1.f / 64.f) - m * m + 1e-5f);
    int il = quad * 4 + r;
    #pragma unroll
    for (int jt = 0; jt < 4; ++jt) {
      int n = jt * 16 + c;
      xa2[il * 72 + n] = f2b((xv[jt][r] - m) * rs * g2[n] + bb2[n]);
    }
  }
  // ---- FF part ----
  const uint16_t* xrow = xa2 + c * 72;
  bfrag8 a0 = *(const bfrag8*)(xrow + quad * 8);
  bfrag8 a1 = *(const bfrag8*)(xrow + 32 + quad * 8);
  ffrag4 acc1[16];
  #pragma unroll
  for (int jt = 0; jt < 16; ++jt) {
    bfrag8 b0  = *(const bfrag8*)(W1t + (size_t)(jt * 16 + c) * 64 + quad * 8);
    bfrag8 b1f = *(const bfrag8*)(W1t + (size_t)(jt * 16 + c) * 64 + 32 + quad * 8);
    ffrag4 z = {0.f, 0.f, 0.f, 0.f};
    z = __builtin_amdgcn_mfma_f32_16x16x32_bf16(a0, b0, z, 0, 0, 0);
    z = __builtin_amdgcn_mfma_f32_16x16x32_bf16(a1, b1f, z, 0, 0, 0);
    acc1[jt] = z;
  }
  #pragma unroll
  for (int jt = 0; jt < 16; ++jt) {
    float bv = b1[jt * 16 + c];
    #pragma unroll
    for (int r = 0; r < 4; ++r) {
      float z = acc1[jt][r] + bv;
      float hg = 0.5f * z * (1.f + erff(z * 0.7071067811865476f));
      ha[(quad * 4 + r) * 264 + jt * 16 + c] = f2b(hg);
    }
  }
  ffrag4 o2[4];
  #pragma unroll
  for (int jt = 0; jt < 4; ++jt) o2[jt] = (ffrag4){0.f, 0.f, 0.f, 0.f};
  #pragma unroll
  for (int kc = 0; kc < 8; ++kc) {
    bfrag8 pa = *(const bfrag8*)(ha + c * 264 + kc * 32 + quad * 8);
    #pragma unroll
    for (int jt = 0; jt < 4; ++jt) {
      bfrag8 vb = *(const bfrag8*)(W2t + (size_t)(jt * 16 + c) * 256 + kc * 32 + quad * 8);
      o2[jt] = __builtin_amdgcn_mfma_f32_16x16x32_bf16(pa, vb, o2[jt], 0, 0, 0);
    }
  }
  float yv[4][4];
  #pragma unroll
  for (int jt = 0; jt < 4; ++jt) {
    float bv = b2[jt * 16 + c];
    #pragma unroll
    for (int r = 0; r < 4; ++r) {
      int il = quad * 4 + r;
      size_t idx = (size_t)(r0 + il) * 64 + jt * 16 + c;
      float v = X[idx] + o2[jt][r] + bv;
      X[idx] = v;
      yv[jt][r] = v;
    }
  }
  #pragma unroll
  for (int r = 0; r < 4; ++r) {
    float s = yv[0][r] + yv[1][r] + yv[2][r] + yv[3][r];
    float q = yv[0][r]*yv[0][r] + yv[1][r]*yv[1][r] + yv[2][r]*yv[2][r] + yv[3][r]*yv[3][r];
    #pragma unroll
    for (int o = 8; o; o >>= 1) { s += __shfl_xor(s, o); q += __shfl_xor(q, o); }
    float m = s * (1.f / 64.f);
    float rs = rsqrtf(q * (1.f / 64.f) - m * m + 1e-5f);
    int il = quad * 4 + r;
    #pragma unroll
    for (int jt = 0; jt < 4; ++jt) {
      int n = jt * 16 + c;
      XnOut[(size_t)(r0 + il) * 64 + n] = f2b((yv[jt][r] - m) * rs * gn[n] + bbn[n]);
    }
  }
}

// ---- swap cls tokens between streams; refresh Xn (LN1 layer0) for those rows ----
__global__ void k_xchg(float* __restrict__ X, uint16_t* __restrict__ Xn,
                       const float* __restrict__ g, const float* __restrict__ bb) {
  int b = blockIdx.x, d = threadIdx.x;   // 64 blocks x 64 threads (1 wave)
  size_t i0 = (size_t)(b * NTOK) * ND + d;
  size_t i1 = (size_t)((64 + b) * NTOK) * ND + d;
  float a = X[i0], cc = X[i1];
  X[i0] = cc; X[i1] = a;
  float s0 = cc, q0 = cc * cc, s1 = a, q1 = a * a;
  #pragma unroll
  for (int o = 32; o; o >>= 1) {
    s0 += __shfl_xor(s0, o); q0 += __shfl_xor(q0, o);
    s1 += __shfl_xor(s1, o); q1 += __shfl_xor(q1, o);
  }
  float m0 = s0 * (1.f / 64.f), rs0 = rsqrtf(q0 * (1.f / 64.f) - m0 * m0 + 1e-5f);
  float m1 = s1 * (1.f / 64.f), rs1 = rsqrtf(q1 * (1.f / 64.f) - m1 * m1 + 1e-5f);
  Xn[i0] = f2b((cc - m0) * rs0 * g[d] + bb[d]);
  Xn[i1] = f2b((a - m1) * rs1 * g[d] + bb[d]);
}

// ---- final: out = h_cls + l_cls ----
__global__ void k_out(const float* __restrict__ X, float* __restrict__ out) {
  int i = blockIdx.x * 64 + threadIdx.x;
  int b = i >> 6, d = i & 63;
  out[i] = X[(size_t)b * NTOK * ND + d] + X[(size_t)(64 + b) * NTOK * ND + d];
}

extern "C" void kernel_launch(void* const* d_in, const int* in_sizes, int n_in,
                              void* d_out, int out_size, void* d_ws, size_t ws_size,
                              hipStream_t stream) {
  const float* hsi   = (const float*)d_in[0];
  const float* lidar = (const float*)d_in[1];
  const float* cls_h = (const float*)d_in[2];
  const float* cls_l = (const float*)d_in[3];
  const float* pos_h = (const float*)d_in[4];
  const float* pos_l = (const float*)d_in[5];
  const float* fmg_w = (const float*)d_in[6];
  const float* ln1_g = (const float*)d_in[7];
  const float* ln1_b = (const float*)d_in[8];
  const float* qkv_w = (const float*)d_in[9];
  const float* out_w = (const float*)d_in[10];
  const float* out_b = (const float*)d_in[11];
  const float* ln2_g = (const float*)d_in[12];
  const float* ln2_b = (const float*)d_in[13];
  const float* ff_w1 = (const float*)d_in[14];
  const float* ff_b1 = (const float*)d_in[15];
  const float* ff_w2 = (const float*)d_in[16];
  const float* ff_b2 = (const float*)d_in[17];

  char* ws = (char*)d_ws;
  float*    X    = (float*)ws;                       // 7,405,568 B
  float*    sdfm = (float*)(ws + 7405568);           // 16,384 B
  uint16_t* Xn   = (uint16_t*)(ws + 7421952);        // 3,702,784 B
  uint16_t* Og   = (uint16_t*)(ws + 11124736);       // 29,622,272 B
  uint16_t* Wqv  = (uint16_t*)(ws + 40747008);       // 524,288 B
  uint16_t* Wo   = (uint16_t*)(ws + 41271296);       // 262,144 B
  uint16_t* W1   = (uint16_t*)(ws + 41533440);       // 131,072 B
  uint16_t* W2   = (uint16_t*)(ws + 41664512);       // 131,072 B -> end 41,795,584

  k_wconv<<<2048, 256, 0, stream>>>(qkv_w, out_w, ff_w1, ff_w2, Wqv, Wo, W1, W2);
  k_dfm<<<NB, 128, 0, stream>>>(hsi, lidar, fmg_w, sdfm);
  k_build<<<NROWS, 64, 0, stream>>>(hsi, cls_h, cls_l, pos_h, pos_l,
                                    ln1_g, ln1_b, X, Xn);
  for (int pass = 0; pass < 2; ++pass) {
    for (int ly = 0; ly < NDEPTH; ++ly) {
      int nx = (ly + 1) & 3;   // next layer's LN1 params (harmless on final layer)
      k_fattn<<<NSB * NH, 512, 0, stream>>>(Xn, Wqv + (size_t)ly * 65536, sdfm, Og);
      k_pf<<<NROWS / 16, 64, 0, stream>>>(Og, Wo + (size_t)ly * 32768, out_b + ly * ND,
                                          X, ln2_g + ly * ND, ln2_b + ly * ND,
                                          W1 + (size_t)ly * 16384, ff_b1 + ly * NMLP,
                                          W2 + (size_t)ly * 16384, ff_b2 + ly * ND,
                                          ln1_g + nx * ND, ln1_b + nx * ND, Xn);
    }
    if (pass == 0) k_xchg<<<64, 64, 0, stream>>>(X, Xn, ln1_g, ln1_b);
  }
  k_out<<<64, 64, 0, stream>>>(X, (float*)d_out);
}